// Round 9
// baseline (208.208 us; speedup 1.0000x reference)
//
#include <hip/hip_runtime.h>

// Problem: B=4, T=2048, C=768, H=12, D=64.  qkv = x@w_qkv^T, rope(q,k),
// causal softmax(q k^T / 8) v, out = y@w_o^T.  All interface fp32; internal bf16.
#define B_  4
#define T_  2048
#define C_  768
#define H_  12
#define D_  64

typedef unsigned short u16;
typedef unsigned int   u32;
typedef __bf16 bf16;
typedef __bf16 bf16x4 __attribute__((ext_vector_type(4)));
typedef __bf16 bf16x8 __attribute__((ext_vector_type(8)));
typedef float  f32x4  __attribute__((ext_vector_type(4)));
typedef __attribute__((address_space(1))) void* gas_t;
typedef __attribute__((address_space(3))) void* las_t;

static __device__ __forceinline__ u16 f2bf(float f) {
  u32 u = __builtin_bit_cast(u32, f);
  u += 0x7FFFu + ((u >> 16) & 1u);          // RNE
  return (u16)(u >> 16);
}

// ---------------- fp32 -> bf16 convert; w_qkv rows PERMUTED within each
// 64-row head group so the GEMM fragment holds rope pairs lane-locally:
// original col d -> fragment col c = ((d&1)|((d>>5)<<1))*16 + ((d>>1)&15.
__global__ __launch_bounds__(256) void k_cvt3(const float* __restrict__ a0,
                                              const float* __restrict__ a1,
                                              const float* __restrict__ a2,
                                              u16* __restrict__ o0,
                                              u16* __restrict__ o1,
                                              u16* __restrict__ o2) {
  const int bid = blockIdx.x;
  const int tid = threadIdx.x;
  if (bid < 6144) {                   // x: flat copy
    const int i = bid * 256 + tid;
    const float4 v = ((const float4*)a0)[i];
    ushort4 o;
    o.x = f2bf(v.x); o.y = f2bf(v.y); o.z = f2bf(v.z); o.w = f2bf(v.w);
    ((ushort4*)o0)[i] = o;
  } else if (bid < 7872) {            // w_qkv: row-permuted copy (q,k only)
    const int i = (bid - 6144) * 256 + tid;       // float4 index
    const int n = i / 192;                         // row (768/4 = 192 f4/row)
    const int c4 = i - n * 192;                    // float4 col within row
    int n2 = n;
    if (n < 1536) {
      const int d = n & 63;
      const int c = (((d & 1) | ((d >> 5) << 1)) << 4) | ((d >> 1) & 15);
      n2 = (n & ~63) | c;
    }
    const float4 v = ((const float4*)a1)[i];
    ushort4 o;
    o.x = f2bf(v.x); o.y = f2bf(v.y); o.z = f2bf(v.z); o.w = f2bf(v.w);
    ((ushort4*)o1)[n2 * 192 + c4] = o;
  } else {                            // w_o: flat copy
    const int i = (bid - 7872) * 256 + tid;
    const float4 v = ((const float4*)a2)[i];
    ushort4 o;
    o.x = f2bf(v.x); o.y = f2bf(v.y); o.z = f2bf(v.z); o.w = f2bf(v.w);
    ((ushort4*)o2)[i] = o;
  }
}

// ---------------- GEMM: C[m,n] = sum_k A[m,k]*Bt[n,k]  (bf16 in)
// 128x128 tile, BK=32, 4 waves, 16x16x32 MFMA, XCD swizzle.
// MODE 1: f32 C out.  MODE 2: fused qkv epilogue -- rope+relayout q,k to
// (b,h,t,d) bf16 (q pre-scaled by 0.125*log2e), v to compact [b*T, 768] buffer.
template<int MODE>
__global__ __launch_bounds__(256) void k_gemm_bt(const u16* __restrict__ A,
                                                 const u16* __restrict__ Bt,
                                                 float* __restrict__ Cout,
                                                 u16* __restrict__ qout,
                                                 u16* __restrict__ kout,
                                                 u16* __restrict__ vout,
                                                 const float* __restrict__ rope,
                                                 int M, int N, int K) {
  __shared__ u16 lA[128 * 32];
  __shared__ u16 lB[128 * 32];
  const int tid = threadIdx.x;
  const int l = tid & 63, w = tid >> 6;
  const int lo = l & 15, hi = l >> 4;
  const int wr = w >> 1, wc = w & 1;
  const int pid = blockIdx.x + gridDim.x * blockIdx.y;
  const int total = gridDim.x * gridDim.y;
  const int lid = (pid & 7) * (total >> 3) + (pid >> 3);
  const int bx = lid % gridDim.x, by = lid / gridDim.x;
  const int m0 = by * 128, n0 = bx * 128;

  f32x4 acc[4][4] = {};
  for (int k0 = 0; k0 < K; k0 += 32) {
#pragma unroll
    for (int r = 0; r < 2; ++r) {
      const int c = tid + 256 * r;
      const int row = c >> 2, cb = (c & 3) * 8;
      __builtin_amdgcn_global_load_lds((gas_t)(u16*)(A + (size_t)(m0 + row) * K + k0 + cb),
                                       (las_t)(lA + c * 8), 16, 0, 0);
      __builtin_amdgcn_global_load_lds((gas_t)(u16*)(Bt + (size_t)(n0 + row) * K + k0 + cb),
                                       (las_t)(lB + c * 8), 16, 0, 0);
    }
    __syncthreads();
    bf16x8 af[4], bfr[4];
#pragma unroll
    for (int i = 0; i < 4; ++i)
      af[i] = *(const bf16x8*)(lA + (wr * 64 + i * 16 + lo) * 32 + hi * 8);
#pragma unroll
    for (int j = 0; j < 4; ++j)
      bfr[j] = *(const bf16x8*)(lB + (wc * 64 + j * 16 + lo) * 32 + hi * 8);
#pragma unroll
    for (int i = 0; i < 4; ++i)
#pragma unroll
      for (int j = 0; j < 4; ++j)
        acc[i][j] = __builtin_amdgcn_mfma_f32_16x16x32_bf16(af[i], bfr[j], acc[i][j], 0, 0, 0);
    __syncthreads();
  }
  const int crow = m0 + wr * 64;
  if (MODE == 1) {
    const int ccol = n0 + wc * 64;
#pragma unroll
    for (int i = 0; i < 4; ++i)
#pragma unroll
      for (int j = 0; j < 4; ++j)
#pragma unroll
        for (int r = 0; r < 4; ++r)
          Cout[(size_t)(crow + i * 16 + hi * 4 + r) * N + ccol + j * 16 + lo] = acc[i][j][r];
  } else {
    const int sect = bx / 6;              // 0 q, 1 k, 2 v
    const int h2 = (bx % 6) * 2 + wc;     // head 0..11
    if (sect < 2) {
      // permuted cols: acc[i][0/1] = d (2lo, 2lo+1); acc[i][2/3] = (32+2lo, 33+2lo)
      const float qsc = (sect == 0) ? 0.18033688011f : 1.0f;   // 0.125*log2(e)
      u16* dst = (sect == 0) ? qout : kout;
#pragma unroll
      for (int i = 0; i < 4; ++i)
#pragma unroll
        for (int r = 0; r < 4; ++r) {
          const int trow = crow + i * 16 + hi * 4 + r;
          const int t = trow & (T_ - 1), bb = trow >> 11;
          const float2 cs0 = *(const float2*)(rope + ((size_t)t * 32 + lo) * 2);
          const float2 cs1 = *(const float2*)(rope + ((size_t)t * 32 + 16 + lo) * 2);
          const float a0 = acc[i][0][r], a1 = acc[i][1][r];
          const float a2 = acc[i][2][r], a3 = acc[i][3][r];
          const float e0 = (a0 * cs0.x - a1 * cs0.y) * qsc;
          const float e1 = (a0 * cs0.y + a1 * cs0.x) * qsc;
          const float e2 = (a2 * cs1.x - a3 * cs1.y) * qsc;
          const float e3 = (a2 * cs1.y + a3 * cs1.x) * qsc;
          u16* row = dst + ((size_t)(bb * H_ + h2) * T_ + t) * D_;
          *(ushort2*)(row + 2 * lo)      = make_ushort2(f2bf(e0), f2bf(e1));
          *(ushort2*)(row + 32 + 2 * lo) = make_ushort2(f2bf(e2), f2bf(e3));
        }
    } else {
      // v: unpermuted cols, write compact [trow][h2*64 + c]
#pragma unroll
      for (int i = 0; i < 4; ++i)
#pragma unroll
        for (int j = 0; j < 4; ++j)
#pragma unroll
          for (int r = 0; r < 4; ++r) {
            const int trow = crow + i * 16 + hi * 4 + r;
            vout[(size_t)trow * C_ + h2 * D_ + j * 16 + lo] = f2bf(acc[i][j][r]);
          }
    }
  }
}

// ---------------- V transpose: compact v [b*T, 768] -> Vt (b,h,d,t)
__global__ __launch_bounds__(256) void k_vtrans(const u16* __restrict__ vtmp,
                                                u16* __restrict__ vt) {
  __shared__ u16 lds[64][68];
  const int bid = blockIdx.x;
  const int ttile = bid & 31, bh = bid >> 5;
  const int b = bh / H_, h = bh % H_;
  const int tid = threadIdx.x;
  const int tl = tid >> 2, doff = (tid & 3) * 16;
  const u16* src = vtmp + (size_t)(b * T_ + ttile * 64 + tl) * C_ + h * D_ + doff;
  const uint4 v0 = *(const uint4*)(src);
  const uint4 v1 = *(const uint4*)(src + 8);
  *(uint2*)&lds[tl][doff + 0]  = make_uint2(v0.x, v0.y);
  *(uint2*)&lds[tl][doff + 4]  = make_uint2(v0.z, v0.w);
  *(uint2*)&lds[tl][doff + 8]  = make_uint2(v1.x, v1.y);
  *(uint2*)&lds[tl][doff + 12] = make_uint2(v1.z, v1.w);
  __syncthreads();
  const int d = tl, toff = doff;
  uint4 o0, o1;
#define PK(j) ((u32)lds[toff + (j)][d] | ((u32)lds[toff + (j) + 1][d] << 16))
  o0.x = PK(0);  o0.y = PK(2);  o0.z = PK(4);  o0.w = PK(6);
  o1.x = PK(8);  o1.y = PK(10); o1.z = PK(12); o1.w = PK(14);
#undef PK
  u16* dst = vt + ((size_t)bh * D_ + d) * T_ + ttile * 64 + toff;
  *(uint4*)(dst) = o0;
  *(uint4*)(dst + 8) = o1;
}

// ---------------- flash attention v9: barrier-free, LDS-free K/V
// One WAVE per block (64 thr), 32 q rows/wave, kv tile 64.  K and Vt
// fragments load straight from global (L2-resident: 512 KB/head; XCD-grouped
// mapping keeps the 6 heads of one XCD in its 4 MB L2).  P-transpose uses a
// tiny per-wave LDS buffer (wave-internal DS ordering) -- the kernel has NO
// barriers and NO staging, so 12+ independent waves/CU drift freely and fill
// each other's stalls.  __launch_bounds__(64,4) caps VGPR at 128.
__global__ __launch_bounds__(64, 4) void k_attn(const u16* __restrict__ qb,
                                                const u16* __restrict__ kb,
                                                const u16* __restrict__ vtb,
                                                u16* __restrict__ yb) {
  __shared__ u16 pbuf[32 * 72];
  const int l = threadIdx.x;                 // 0..63
  const int lo = l & 15, hi = l >> 4;
  // 3072 waves = 8 XCD x (64 q-tiles x 6 bh), heavy q first within each XCD
  const int pid = blockIdx.x;
  const int xcd = pid & 7;
  const int rank = pid >> 3;                 // 0..383
  const int qi = rank / 6;                   // 0 = heaviest
  const int bh = xcd * 6 + (rank % 6);       // 0..47
  const int h = bh % H_, b = bh / H_;
  const int q0w = (63 - qi) * 32;            // wave's 32 q rows
  const u16* Q  = qb  + (size_t)bh * T_ * D_;
  const u16* K  = kb  + (size_t)bh * T_ * D_;
  const u16* Vt = vtb + (size_t)bh * D_ * T_;

  const bf16x8 qf0 = *(const bf16x8*)(Q + (size_t)(q0w + lo) * D_ + hi * 8);
  const bf16x8 qf1 = *(const bf16x8*)(Q + (size_t)(q0w + lo) * D_ + 32 + hi * 8);
  const bf16x8 qf2 = *(const bf16x8*)(Q + (size_t)(q0w + 16 + lo) * D_ + hi * 8);
  const bf16x8 qf3 = *(const bf16x8*)(Q + (size_t)(q0w + 16 + lo) * D_ + 32 + hi * 8);
  float lsum0 = 0.f, lsum1 = 0.f;
  f32x4 o0[4] = {}, o1[4] = {};

  const int nt = (q0w >> 6) + 1;             // exact per-wave tile count
  for (int t = 0; t < nt; ++t) {
    const int j0 = t * 64;
    f32x4 s[4]  = {{0.f,0.f,0.f,0.f},{0.f,0.f,0.f,0.f},{0.f,0.f,0.f,0.f},{0.f,0.f,0.f,0.f}};
    f32x4 s2[4] = {{0.f,0.f,0.f,0.f},{0.f,0.f,0.f,0.f},{0.f,0.f,0.f,0.f},{0.f,0.f,0.f,0.f}};
    __builtin_amdgcn_s_setprio(1);
#pragma unroll
    for (int f = 0; f < 4; ++f) {
      const u16* krow = K + (size_t)(j0 + 16 * f + lo) * D_;
      const bf16x8 kd0 = *(const bf16x8*)(krow + hi * 8);
      const bf16x8 kd1 = *(const bf16x8*)(krow + 32 + hi * 8);
      s[f]  = __builtin_amdgcn_mfma_f32_16x16x32_bf16(kd0, qf0, s[f],  0, 0, 0);
      s[f]  = __builtin_amdgcn_mfma_f32_16x16x32_bf16(kd1, qf1, s[f],  0, 0, 0);
      s2[f] = __builtin_amdgcn_mfma_f32_16x16x32_bf16(kd0, qf2, s2[f], 0, 0, 0);
      s2[f] = __builtin_amdgcn_mfma_f32_16x16x32_bf16(kd1, qf3, s2[f], 0, 0, 0);
    }
    __builtin_amdgcn_s_setprio(0);
    if (t == nt - 1) {                     // only the diagonal tile masks
#pragma unroll
      for (int f = 0; f < 4; ++f)
#pragma unroll
        for (int r = 0; r < 4; ++r) {
          const int kv = j0 + 16 * f + 4 * hi + r;
          if (kv > q0w + lo)      s[f][r]  = -1e30f;
          if (kv > q0w + 16 + lo) s2[f][r] = -1e30f;
        }
    }
    // P = exp2(S) (q carries log2e/sqrt(D)); lane-local l accumulation
#pragma unroll
    for (int f = 0; f < 4; ++f)
#pragma unroll
      for (int r = 0; r < 4; ++r) {
        const float p0 = exp2f(s[f][r]);
        const float p1 = exp2f(s2[f][r]);
        s[f][r] = p0; s2[f][r] = p1;
        lsum0 += p0; lsum1 += p1;
      }
    // P -> per-wave LDS (rows = q 0..31, cols = kv, stride 72); no barriers:
    // wave-internal DS ordering guarantees read-after-write.
#pragma unroll
    for (int f = 0; f < 4; ++f) {
      bf16x4 pk0, pk1;
      pk0[0] = (__bf16)s[f][0];  pk0[1] = (__bf16)s[f][1];
      pk0[2] = (__bf16)s[f][2];  pk0[3] = (__bf16)s[f][3];
      pk1[0] = (__bf16)s2[f][0]; pk1[1] = (__bf16)s2[f][1];
      pk1[2] = (__bf16)s2[f][2]; pk1[3] = (__bf16)s2[f][3];
      *(bf16x4*)(pbuf + lo * 72 + 16 * f + 4 * hi)        = pk0;
      *(bf16x4*)(pbuf + (16 + lo) * 72 + 16 * f + 4 * hi) = pk1;
    }
    const bf16x8 pf0h0 = *(const bf16x8*)(pbuf + lo * 72 + hi * 8);
    const bf16x8 pf1h0 = *(const bf16x8*)(pbuf + lo * 72 + 32 + hi * 8);
    const bf16x8 pf0h1 = *(const bf16x8*)(pbuf + (16 + lo) * 72 + hi * 8);
    const bf16x8 pf1h1 = *(const bf16x8*)(pbuf + (16 + lo) * 72 + 32 + hi * 8);
    // PV swapped: O^T[d][q] += Vt_frag * P_frag; V fragments from global (L2)
    __builtin_amdgcn_s_setprio(1);
#pragma unroll
    for (int n = 0; n < 4; ++n) {
      const u16* vrow = Vt + (size_t)(n * 16 + lo) * T_ + j0;
      const bf16x8 vf0 = *(const bf16x8*)(vrow + hi * 8);
      const bf16x8 vf1 = *(const bf16x8*)(vrow + 32 + hi * 8);
      o0[n] = __builtin_amdgcn_mfma_f32_16x16x32_bf16(vf0, pf0h0, o0[n], 0, 0, 0);
      o0[n] = __builtin_amdgcn_mfma_f32_16x16x32_bf16(vf1, pf1h0, o0[n], 0, 0, 0);
      o1[n] = __builtin_amdgcn_mfma_f32_16x16x32_bf16(vf0, pf0h1, o1[n], 0, 0, 0);
      o1[n] = __builtin_amdgcn_mfma_f32_16x16x32_bf16(vf1, pf1h1, o1[n], 0, 0, 0);
    }
    __builtin_amdgcn_s_setprio(0);
  }
  float lt0 = lsum0;
  lt0 += __shfl_xor(lt0, 16); lt0 += __shfl_xor(lt0, 32);
  float lt1 = lsum1;
  lt1 += __shfl_xor(lt1, 16); lt1 += __shfl_xor(lt1, 32);
  const float li0 = 1.0f / lt0, li1 = 1.0f / lt1;
  u16* yr0 = yb + (size_t)(b * T_ + q0w + lo) * C_ + h * D_ + 4 * hi;
  u16* yr1 = yb + (size_t)(b * T_ + q0w + 16 + lo) * C_ + h * D_ + 4 * hi;
#pragma unroll
  for (int n = 0; n < 4; ++n) {
    bf16x4 ok0, ok1;
#pragma unroll
    for (int r = 0; r < 4; ++r) {
      ok0[r] = (__bf16)(o0[n][r] * li0);
      ok1[r] = (__bf16)(o1[n][r] * li1);
    }
    *(bf16x4*)(yr0 + n * 16) = ok0;
    *(bf16x4*)(yr1 + n * 16) = ok1;
  }
}

extern "C" void kernel_launch(void* const* d_in, const int* in_sizes, int n_in,
                              void* d_out, int out_size, void* d_ws, size_t ws_size,
                              hipStream_t stream) {
  (void)in_sizes; (void)n_in; (void)out_size; (void)ws_size;
  const float* x    = (const float*)d_in[0];
  const float* rope = (const float*)d_in[1];
  const float* wqkv = (const float*)d_in[2];
  const float* wo   = (const float*)d_in[3];
  float* out = (float*)d_out;
  char* ws = (char*)d_ws;
  u16* xb    = (u16*)(ws);              // 12582912  (8192x768 bf16) -- reused as yb
  u16* wqkvb = (u16*)(ws + 12582912);   //  3538944  (2304x768, row-permuted)
  u16* wob   = (u16*)(ws + 16121856);   //  1179648  (768x768)
  u16* vtmp  = (u16*)(ws + 17301504);   // 12582912  (compact v [b*T,768])
  u16* qb    = (u16*)(ws + 55050240);   // 12582912  (b,h,t,d)
  u16* kb    = (u16*)(ws + 67633152);   // 12582912  (b,h,t,d)
  u16* vtb   = (u16*)(ws + 80216064);   // 12582912  (b,h,d,t)
  u16* yb    = xb;                      // x is dead after QKV GEMM

  k_cvt3<<<8448, 256, 0, stream>>>(x, wqkv, wo, xb, wqkvb, wob);
  k_gemm_bt<2><<<dim3(18, 64), 256, 0, stream>>>(xb, wqkvb, nullptr, qb, kb, vtmp,
                                                 rope, 8192, 2304, 768);
  k_vtrans<<<1536, 256, 0, stream>>>(vtmp, vtb);
  k_attn<<<3072, 64, 0, stream>>>(qb, kb, vtb, yb);
  k_gemm_bt<1><<<dim3(6, 64), 256, 0, stream>>>(yb, wob, out, nullptr, nullptr, nullptr,
                                                nullptr, 8192, 768, 768);
}

// Round 10
// 151.399 us; speedup vs baseline: 1.3752x; 1.3752x over previous
//
#include <hip/hip_runtime.h>

// Problem: B=4, T=2048, C=768, H=12, D=64.  qkv = x@w_qkv^T, rope(q,k),
// causal softmax(q k^T / 8) v, out = y@w_o^T.  All interface fp32; internal bf16.
#define B_  4
#define T_  2048
#define C_  768
#define H_  12
#define D_  64

typedef unsigned short u16;
typedef unsigned int   u32;
typedef __bf16 bf16;
typedef __bf16 bf16x4 __attribute__((ext_vector_type(4)));
typedef __bf16 bf16x8 __attribute__((ext_vector_type(8)));
typedef float  f32x4  __attribute__((ext_vector_type(4)));
typedef float  f32x16 __attribute__((ext_vector_type(16)));
typedef u32    u32x4  __attribute__((ext_vector_type(4)));
typedef __attribute__((address_space(1))) void* gas_t;
typedef __attribute__((address_space(3))) void* las_t;

static __device__ __forceinline__ u16 f2bf(float f) {
  u32 u = __builtin_bit_cast(u32, f);
  u += 0x7FFFu + ((u >> 16) & 1u);          // RNE
  return (u16)(u >> 16);
}

// v_cvt_pk_bf16_f32: dst.lo = bf16(a), dst.hi = bf16(b)  (RTNE)
static __device__ __forceinline__ u32 cvtpk(float a, float b) {
  u32 r;
  asm("v_cvt_pk_bf16_f32 %0, %1, %2" : "=v"(r) : "v"(a), "v"(b));
  return r;
}
// v_permlane32_swap_b32: a[32..63] <-> b[0..31]
static __device__ __forceinline__ void plswap(u32& a, u32& b) {
  asm volatile("v_permlane32_swap_b32 %0, %1" : "+v"(a), "+v"(b));
}

// ---------------- fp32 -> bf16 convert; w_qkv rows PERMUTED within each
// 64-row head group so the GEMM fragment holds rope pairs lane-locally:
// original col d -> fragment col c = ((d&1)|((d>>5)<<1))*16 + ((d>>1)&15.
__global__ __launch_bounds__(256) void k_cvt3(const float* __restrict__ a0,
                                              const float* __restrict__ a1,
                                              const float* __restrict__ a2,
                                              u16* __restrict__ o0,
                                              u16* __restrict__ o1,
                                              u16* __restrict__ o2) {
  const int bid = blockIdx.x;
  const int tid = threadIdx.x;
  if (bid < 6144) {                   // x: flat copy
    const int i = bid * 256 + tid;
    const float4 v = ((const float4*)a0)[i];
    ushort4 o;
    o.x = f2bf(v.x); o.y = f2bf(v.y); o.z = f2bf(v.z); o.w = f2bf(v.w);
    ((ushort4*)o0)[i] = o;
  } else if (bid < 7872) {            // w_qkv: row-permuted copy (q,k only)
    const int i = (bid - 6144) * 256 + tid;       // float4 index
    const int n = i / 192;                         // row (768/4 = 192 f4/row)
    const int c4 = i - n * 192;                    // float4 col within row
    int n2 = n;
    if (n < 1536) {
      const int d = n & 63;
      const int c = (((d & 1) | ((d >> 5) << 1)) << 4) | ((d >> 1) & 15);
      n2 = (n & ~63) | c;
    }
    const float4 v = ((const float4*)a1)[i];
    ushort4 o;
    o.x = f2bf(v.x); o.y = f2bf(v.y); o.z = f2bf(v.z); o.w = f2bf(v.w);
    ((ushort4*)o1)[n2 * 192 + c4] = o;
  } else {                            // w_o: flat copy
    const int i = (bid - 7872) * 256 + tid;
    const float4 v = ((const float4*)a2)[i];
    ushort4 o;
    o.x = f2bf(v.x); o.y = f2bf(v.y); o.z = f2bf(v.z); o.w = f2bf(v.w);
    ((ushort4*)o2)[i] = o;
  }
}

// ---------------- GEMM: C[m,n] = sum_k A[m,k]*Bt[n,k]  (bf16 in)
// 128x128 tile, BK=32, 4 waves, 16x16x32 MFMA, XCD swizzle.
// MODE 1: f32 C out.  MODE 2: fused qkv epilogue -- rope+relayout q,k to
// (b,h,t,d) bf16 (q pre-scaled by 0.125*log2e), v to compact [b*T, 768] buffer.
template<int MODE>
__global__ __launch_bounds__(256) void k_gemm_bt(const u16* __restrict__ A,
                                                 const u16* __restrict__ Bt,
                                                 float* __restrict__ Cout,
                                                 u16* __restrict__ qout,
                                                 u16* __restrict__ kout,
                                                 u16* __restrict__ vout,
                                                 const float* __restrict__ rope,
                                                 int M, int N, int K) {
  __shared__ u16 lA[128 * 32];
  __shared__ u16 lB[128 * 32];
  const int tid = threadIdx.x;
  const int l = tid & 63, w = tid >> 6;
  const int lo = l & 15, hi = l >> 4;
  const int wr = w >> 1, wc = w & 1;
  const int pid = blockIdx.x + gridDim.x * blockIdx.y;
  const int total = gridDim.x * gridDim.y;
  const int lid = (pid & 7) * (total >> 3) + (pid >> 3);
  const int bx = lid % gridDim.x, by = lid / gridDim.x;
  const int m0 = by * 128, n0 = bx * 128;

  f32x4 acc[4][4] = {};
  for (int k0 = 0; k0 < K; k0 += 32) {
#pragma unroll
    for (int r = 0; r < 2; ++r) {
      const int c = tid + 256 * r;
      const int row = c >> 2, cb = (c & 3) * 8;
      __builtin_amdgcn_global_load_lds((gas_t)(u16*)(A + (size_t)(m0 + row) * K + k0 + cb),
                                       (las_t)(lA + c * 8), 16, 0, 0);
      __builtin_amdgcn_global_load_lds((gas_t)(u16*)(Bt + (size_t)(n0 + row) * K + k0 + cb),
                                       (las_t)(lB + c * 8), 16, 0, 0);
    }
    __syncthreads();
    bf16x8 af[4], bfr[4];
#pragma unroll
    for (int i = 0; i < 4; ++i)
      af[i] = *(const bf16x8*)(lA + (wr * 64 + i * 16 + lo) * 32 + hi * 8);
#pragma unroll
    for (int j = 0; j < 4; ++j)
      bfr[j] = *(const bf16x8*)(lB + (wc * 64 + j * 16 + lo) * 32 + hi * 8);
#pragma unroll
    for (int i = 0; i < 4; ++i)
#pragma unroll
      for (int j = 0; j < 4; ++j)
        acc[i][j] = __builtin_amdgcn_mfma_f32_16x16x32_bf16(af[i], bfr[j], acc[i][j], 0, 0, 0);
    __syncthreads();
  }
  const int crow = m0 + wr * 64;
  if (MODE == 1) {
    const int ccol = n0 + wc * 64;
#pragma unroll
    for (int i = 0; i < 4; ++i)
#pragma unroll
      for (int j = 0; j < 4; ++j)
#pragma unroll
        for (int r = 0; r < 4; ++r)
          Cout[(size_t)(crow + i * 16 + hi * 4 + r) * N + ccol + j * 16 + lo] = acc[i][j][r];
  } else {
    const int sect = bx / 6;              // 0 q, 1 k, 2 v
    const int h2 = (bx % 6) * 2 + wc;     // head 0..11
    if (sect < 2) {
      // permuted cols: acc[i][0/1] = d (2lo, 2lo+1); acc[i][2/3] = (32+2lo, 33+2lo)
      const float qsc = (sect == 0) ? 0.18033688011f : 1.0f;   // 0.125*log2(e)
      u16* dst = (sect == 0) ? qout : kout;
#pragma unroll
      for (int i = 0; i < 4; ++i)
#pragma unroll
        for (int r = 0; r < 4; ++r) {
          const int trow = crow + i * 16 + hi * 4 + r;
          const int t = trow & (T_ - 1), bb = trow >> 11;
          const float2 cs0 = *(const float2*)(rope + ((size_t)t * 32 + lo) * 2);
          const float2 cs1 = *(const float2*)(rope + ((size_t)t * 32 + 16 + lo) * 2);
          const float a0 = acc[i][0][r], a1 = acc[i][1][r];
          const float a2 = acc[i][2][r], a3 = acc[i][3][r];
          const float e0 = (a0 * cs0.x - a1 * cs0.y) * qsc;
          const float e1 = (a0 * cs0.y + a1 * cs0.x) * qsc;
          const float e2 = (a2 * cs1.x - a3 * cs1.y) * qsc;
          const float e3 = (a2 * cs1.y + a3 * cs1.x) * qsc;
          u16* row = dst + ((size_t)(bb * H_ + h2) * T_ + t) * D_;
          *(ushort2*)(row + 2 * lo)      = make_ushort2(f2bf(e0), f2bf(e1));
          *(ushort2*)(row + 32 + 2 * lo) = make_ushort2(f2bf(e2), f2bf(e3));
        }
    } else {
      // v: unpermuted cols, write compact [trow][h2*64 + c]
#pragma unroll
      for (int i = 0; i < 4; ++i)
#pragma unroll
        for (int j = 0; j < 4; ++j)
#pragma unroll
          for (int r = 0; r < 4; ++r) {
            const int trow = crow + i * 16 + hi * 4 + r;
            vout[(size_t)trow * C_ + h2 * D_ + j * 16 + lo] = f2bf(acc[i][j][r]);
          }
    }
  }
}

// ---------------- V transpose: compact v [b*T, 768] -> Vt (b,h,d,t)
__global__ __launch_bounds__(256) void k_vtrans(const u16* __restrict__ vtmp,
                                                u16* __restrict__ vt) {
  __shared__ u16 lds[64][68];
  const int bid = blockIdx.x;
  const int ttile = bid & 31, bh = bid >> 5;
  const int b = bh / H_, h = bh % H_;
  const int tid = threadIdx.x;
  const int tl = tid >> 2, doff = (tid & 3) * 16;
  const u16* src = vtmp + (size_t)(b * T_ + ttile * 64 + tl) * C_ + h * D_ + doff;
  const uint4 v0 = *(const uint4*)(src);
  const uint4 v1 = *(const uint4*)(src + 8);
  *(uint2*)&lds[tl][doff + 0]  = make_uint2(v0.x, v0.y);
  *(uint2*)&lds[tl][doff + 4]  = make_uint2(v0.z, v0.w);
  *(uint2*)&lds[tl][doff + 8]  = make_uint2(v1.x, v1.y);
  *(uint2*)&lds[tl][doff + 12] = make_uint2(v1.z, v1.w);
  __syncthreads();
  const int d = tl, toff = doff;
  uint4 o0, o1;
#define PK(j) ((u32)lds[toff + (j)][d] | ((u32)lds[toff + (j) + 1][d] << 16))
  o0.x = PK(0);  o0.y = PK(2);  o0.z = PK(4);  o0.w = PK(6);
  o1.x = PK(8);  o1.y = PK(10); o1.z = PK(12); o1.w = PK(14);
#undef PK
  u16* dst = vt + ((size_t)bh * D_ + d) * T_ + ttile * 64 + toff;
  *(uint4*)(dst) = o0;
  *(uint4*)(dst + 8) = o1;
}

// ---------------- flash attention v10: 32x32 MFMA + in-register P (T12)
// Base = v8 (4 waves x 32 q, kv tile 64, dbuf swizzled staging, vmcnt(4),
// serpentine heavy-first XCD order).  QK^T swapped at 32x32x16: lane
// (q=l&31, hf=l>>5) holds 16 S-values for ONE q column.  Shift-free softmax
// is fully lane-local.  P -> PV B-fragments via 16 v_cvt_pk_bf16_f32 +
// 8 v_permlane32_swap_b32 -- NO P LDS round-trip.  PV swapped at 32x32x16:
// O^T[d][q], l-normalization lane-local (1 shfl at segment end).
__global__ __launch_bounds__(256) void k_attn(const u16* __restrict__ qb,
                                              const u16* __restrict__ kb,
                                              const u16* __restrict__ vtb,
                                              u16* __restrict__ yb) {
  __shared__ u16 kbuf[2][64 * 64];
  __shared__ u16 vbuf[2][64 * 64];
  const int tid = threadIdx.x;
  const int w = tid >> 6, l = tid & 63;
  const int q5 = l & 31, hf = l >> 5;
  // 768 blocks: xcd = pid&7; rank -> serpentine heavy-first (bx 15..0)
  const int pid = blockIdx.x;
  const int xcd = pid & 7;
  const int rank = pid >> 3;                 // 0..95
  const int wv = rank >> 5, ps = rank & 31;
  const int widx = wv * 32 + ((wv & 1) ? 31 - ps : ps);
  const int bh_local = widx % 6;
  const int bx = 15 - widx / 6;              // heavy (large bx) first
  const int bh = xcd * 6 + bh_local;         // 0..47
  const int h = bh % H_, b = bh / H_;
  const u16* Q  = qb  + (size_t)bh * T_ * D_;
  const u16* K  = kb  + (size_t)bh * T_ * D_;
  const u16* Vt = vtb + (size_t)bh * D_ * T_;
  const int nt = 2 * bx + 2;                 // kv tiles 0..nt-1
  const int q0w = bx * 128 + w * 32;         // wave's 32 q rows
  const int q = q0w + q5;                    // this lane's q column

  const int srow = tid >> 3;
  const int scb  = ((tid & 7) * 16) ^ ((srow & 7) << 4);

#define STAGE(bufi, j0s)                                                             \
  do {                                                                               \
    __builtin_amdgcn_global_load_lds((gas_t)(u16*)(K + (size_t)((j0s) + srow) * D_ + (scb >> 1)),      \
                                     (las_t)(&kbuf[bufi][0] + tid * 8), 16, 0, 0);   \
    __builtin_amdgcn_global_load_lds((gas_t)(u16*)(K + (size_t)((j0s) + 32 + srow) * D_ + (scb >> 1)), \
                                     (las_t)(&kbuf[bufi][0] + (tid + 256) * 8), 16, 0, 0);             \
    __builtin_amdgcn_global_load_lds((gas_t)(u16*)(Vt + (size_t)srow * T_ + (j0s) + (scb >> 1)),       \
                                     (las_t)(&vbuf[bufi][0] + tid * 8), 16, 0, 0);   \
    __builtin_amdgcn_global_load_lds((gas_t)(u16*)(Vt + (size_t)(32 + srow) * T_ + (j0s) + (scb >> 1)),\
                                     (las_t)(&vbuf[bufi][0] + (tid + 256) * 8), 16, 0, 0);             \
  } while (0)

  // Q fragments: B-operand col=q, k = dchunk*16 + hf*8 + j
  bf16x8 qf[4];
#pragma unroll
  for (int dc = 0; dc < 4; ++dc)
    qf[dc] = *(const bf16x8*)(Q + (size_t)q * D_ + dc * 16 + hf * 8);

  const f32x16 Z = {};                  // hoisted zero accumulator seed
  f32x16 o0 = {}, o1 = {};              // O^T rows d=0..31 / 32..63
  float lsum = 0.f;

  STAGE(0, 0);
  asm volatile("s_waitcnt vmcnt(0)" ::: "memory");
  __builtin_amdgcn_s_barrier();
  __builtin_amdgcn_sched_barrier(0);
  int cur = 0;
  for (int t = 0; t < nt; ++t) {
    const int j0 = t * 64;
    if (t + 1 < nt) {
      STAGE(cur ^ 1, (t + 1) * 64);
      asm volatile("s_waitcnt vmcnt(4)" ::: "memory");
    } else {
      asm volatile("s_waitcnt vmcnt(0)" ::: "memory");
    }
    __builtin_amdgcn_s_barrier();
    __builtin_amdgcn_sched_barrier(0);
    if (j0 <= q0w + 31) {                  // causal: wave has live columns
      const u16* kb_l = &kbuf[cur][0];
      const u16* vb_l = &vbuf[cur][0];
      const int swz = (l & 7) << 4;
#pragma unroll
      for (int st = 0; st < 2; ++st) {     // two 32-kv S-tiles
        // ---- QK^T: S[kv=j0+32st+row][q], chained over 4 d-chunks
        f32x16 s;
        __builtin_amdgcn_s_setprio(1);
        {
          const int krow = st * 32 + q5;
          const bf16x8 kd0 = *(const bf16x8*)(kb_l + krow * 64 + (((0   + 16 * hf) ^ swz) >> 1));
          s = __builtin_amdgcn_mfma_f32_32x32x16_bf16(kd0, qf[0], Z, 0, 0, 0);
          const bf16x8 kd1 = *(const bf16x8*)(kb_l + krow * 64 + (((32  + 16 * hf) ^ swz) >> 1));
          s = __builtin_amdgcn_mfma_f32_32x32x16_bf16(kd1, qf[1], s, 0, 0, 0);
          const bf16x8 kd2 = *(const bf16x8*)(kb_l + krow * 64 + (((64  + 16 * hf) ^ swz) >> 1));
          s = __builtin_amdgcn_mfma_f32_32x32x16_bf16(kd2, qf[2], s, 0, 0, 0);
          const bf16x8 kd3 = *(const bf16x8*)(kb_l + krow * 64 + (((96  + 16 * hf) ^ swz) >> 1));
          s = __builtin_amdgcn_mfma_f32_32x32x16_bf16(kd3, qf[3], s, 0, 0, 0);
        }
        __builtin_amdgcn_s_setprio(0);
        // ---- causal mask (diagonal-crossing tiles only)
        if (j0 + 63 > q0w) {
#pragma unroll
          for (int r = 0; r < 16; ++r) {
            const int kv = j0 + 32 * st + (r & 3) + 8 * (r >> 2) + 4 * hf;
            if (kv > q) s[r] = -1e30f;
          }
        }
        // ---- P = exp2(S) (q carries log2e/sqrt(D)); lane-local l
#pragma unroll
        for (int r = 0; r < 16; ++r) {
          const float p = exp2f(s[r]);
          s[r] = p;
          lsum += p;
        }
        // ---- P -> bf16 PV B-fragments: cvt_pk + permlane32_swap
        u32 a0 = cvtpk(s[0],  s[1]),  b0 = cvtpk(s[4],  s[5]);  plswap(a0, b0);
        u32 a1 = cvtpk(s[2],  s[3]),  b1 = cvtpk(s[6],  s[7]);  plswap(a1, b1);
        u32 a2 = cvtpk(s[8],  s[9]),  b2 = cvtpk(s[12], s[13]); plswap(a2, b2);
        u32 a3 = cvtpk(s[10], s[11]), b3 = cvtpk(s[14], s[15]); plswap(a3, b3);
        const bf16x8 pa0 = __builtin_bit_cast(bf16x8, (u32x4){a0, a1, b0, b1});  // kv slot 2st
        const bf16x8 pa1 = __builtin_bit_cast(bf16x8, (u32x4){a2, a3, b2, b3});  // kv slot 2st+1
        // ---- PV: O^T[d][q] += Vt * P  (A=Vt rows d, k=kv slot of 16)
        __builtin_amdgcn_s_setprio(1);
        {
          const int ks0 = st * 2, ks1 = st * 2 + 1;
          const bf16x8 vf00 = *(const bf16x8*)(vb_l + q5 * 64        + (((ks0 * 32 + 16 * hf) ^ swz) >> 1));
          const bf16x8 vf10 = *(const bf16x8*)(vb_l + (32 + q5) * 64 + (((ks0 * 32 + 16 * hf) ^ swz) >> 1));
          o0 = __builtin_amdgcn_mfma_f32_32x32x16_bf16(vf00, pa0, o0, 0, 0, 0);
          o1 = __builtin_amdgcn_mfma_f32_32x32x16_bf16(vf10, pa0, o1, 0, 0, 0);
          const bf16x8 vf01 = *(const bf16x8*)(vb_l + q5 * 64        + (((ks1 * 32 + 16 * hf) ^ swz) >> 1));
          const bf16x8 vf11 = *(const bf16x8*)(vb_l + (32 + q5) * 64 + (((ks1 * 32 + 16 * hf) ^ swz) >> 1));
          o0 = __builtin_amdgcn_mfma_f32_32x32x16_bf16(vf01, pa1, o0, 0, 0, 0);
          o1 = __builtin_amdgcn_mfma_f32_32x32x16_bf16(vf11, pa1, o1, 0, 0, 0);
        }
        __builtin_amdgcn_s_setprio(0);
      }
    }
    asm volatile("" ::: "memory");
    __builtin_amdgcn_s_barrier();
    __builtin_amdgcn_sched_barrier(0);
    cur ^= 1;
  }
#undef STAGE
  // ---- epilogue: l across the two kv-halves, normalize, store O^T
  const float lt = lsum + __shfl_xor(lsum, 32);
  const float linv = 1.0f / lt;
  u16* yrow = yb + (size_t)(b * T_ + q) * C_ + h * D_;
#pragma unroll
  for (int g = 0; g < 4; ++g) {
    bf16x4 ok0, ok1;
#pragma unroll
    for (int r = 0; r < 4; ++r) {
      ok0[r] = (__bf16)(o0[4 * g + r] * linv);
      ok1[r] = (__bf16)(o1[4 * g + r] * linv);
    }
    *(bf16x4*)(yrow + g * 8 + 4 * hf)      = ok0;   // d = 8g+4hf+0..3
    *(bf16x4*)(yrow + 32 + g * 8 + 4 * hf) = ok1;   // d = 32+8g+4hf+0..3
  }
}

extern "C" void kernel_launch(void* const* d_in, const int* in_sizes, int n_in,
                              void* d_out, int out_size, void* d_ws, size_t ws_size,
                              hipStream_t stream) {
  (void)in_sizes; (void)n_in; (void)out_size; (void)ws_size;
  const float* x    = (const float*)d_in[0];
  const float* rope = (const float*)d_in[1];
  const float* wqkv = (const float*)d_in[2];
  const float* wo   = (const float*)d_in[3];
  float* out = (float*)d_out;
  char* ws = (char*)d_ws;
  u16* xb    = (u16*)(ws);              // 12582912  (8192x768 bf16) -- reused as yb
  u16* wqkvb = (u16*)(ws + 12582912);   //  3538944  (2304x768, row-permuted)
  u16* wob   = (u16*)(ws + 16121856);   //  1179648  (768x768)
  u16* vtmp  = (u16*)(ws + 17301504);   // 12582912  (compact v [b*T,768])
  u16* qb    = (u16*)(ws + 55050240);   // 12582912  (b,h,t,d)
  u16* kb    = (u16*)(ws + 67633152);   // 12582912  (b,h,t,d)
  u16* vtb   = (u16*)(ws + 80216064);   // 12582912  (b,h,d,t)
  u16* yb    = xb;                      // x is dead after QKV GEMM

  k_cvt3<<<8448, 256, 0, stream>>>(x, wqkv, wo, xb, wqkvb, wob);
  k_gemm_bt<2><<<dim3(18, 64), 256, 0, stream>>>(xb, wqkvb, nullptr, qb, kb, vtmp,
                                                 rope, 8192, 2304, 768);
  k_vtrans<<<1536, 256, 0, stream>>>(vtmp, vtb);
  k_attn<<<768, 256, 0, stream>>>(qb, kb, vtb, yb);
  k_gemm_bt<1><<<dim3(6, 64), 256, 0, stream>>>(yb, wob, out, nullptr, nullptr, nullptr,
                                                nullptr, 8192, 768, 768);
}